// Round 1
// baseline (284.254 us; speedup 1.0000x reference)
//
#include <hip/hip_runtime.h>
#include <hip/hip_bf16.h>

#define N_NODES 10000
#define KP      10016   // node count padded to multiple of 32 (zero-padded tail)
#define F       128

typedef float  f32x4  __attribute__((ext_vector_type(4)));
typedef short  bf16x8 __attribute__((ext_vector_type(8)));
typedef short  s16x8  __attribute__((ext_vector_type(8)));

// f32 -> bf16 round-to-nearest-even (finite inputs only)
static __device__ __forceinline__ unsigned short f2bf(float f) {
    unsigned u = __builtin_bit_cast(unsigned, f);
    u += 0x7FFFu + ((u >> 16) & 1u);
    return (unsigned short)(u >> 16);
}

static __device__ __forceinline__ bf16x8 pack8(f32x4 lo, f32x4 hi) {
    bf16x8 r;
    r[0] = (short)f2bf(lo[0]); r[1] = (short)f2bf(lo[1]);
    r[2] = (short)f2bf(lo[2]); r[3] = (short)f2bf(lo[3]);
    r[4] = (short)f2bf(hi[0]); r[5] = (short)f2bf(hi[1]);
    r[6] = (short)f2bf(hi[2]); r[7] = (short)f2bf(hi[3]);
    return r;
}

// ---------------------------------------------------------------------------
// Kernel 1: xwt[f][n] = (X @ W1)[n][f] as bf16, transposed, zero-padded to KP.
// grid 626 x 256; each block does 16 nodes x 128 features.
// ---------------------------------------------------------------------------
__global__ __launch_bounds__(256) void k_xw(const float* __restrict__ x,
                                            const float* __restrict__ W1,
                                            unsigned short* __restrict__ xwt) {
    __shared__ float xs[16][128];              // 8 KB
    __shared__ unsigned short ts[16][136];     // transpose staging (padded)
    const int t  = threadIdx.x;
    const int nb = blockIdx.x * 16;

    // stage 16 x-rows (clamped; pad nodes zeroed at write)
    #pragma unroll
    for (int i = 0; i < 2; ++i) {
        int idx = t + i * 256;         // float4 index, 512 total
        int n   = idx >> 5;            // 32 float4 per row
        int c4  = idx & 31;
        int gn  = nb + n; if (gn > N_NODES - 1) gn = N_NODES - 1;
        f32x4 v = *reinterpret_cast<const f32x4*>(x + (size_t)gn * F + c4 * 4);
        *reinterpret_cast<f32x4*>(&xs[n][c4 * 4]) = v;
    }
    __syncthreads();

    const int f  = t & 127;
    const int ng = t >> 7;             // 0..1 -> nodes ng*8..+8
    float acc[8] = {0.f, 0.f, 0.f, 0.f, 0.f, 0.f, 0.f, 0.f};

    for (int c4 = 0; c4 < 32; ++c4) {
        float w0 = W1[(4 * c4 + 0) * F + f];
        float w1 = W1[(4 * c4 + 1) * F + f];
        float w2 = W1[(4 * c4 + 2) * F + f];
        float w3 = W1[(4 * c4 + 3) * F + f];
        #pragma unroll
        for (int i = 0; i < 8; ++i) {
            f32x4 xv = *reinterpret_cast<const f32x4*>(&xs[ng * 8 + i][c4 * 4]);
            acc[i] = fmaf(xv.x, w0, fmaf(xv.y, w1, fmaf(xv.z, w2, fmaf(xv.w, w3, acc[i]))));
        }
    }

    #pragma unroll
    for (int i = 0; i < 8; ++i) ts[ng * 8 + i][f] = f2bf(acc[i]);
    __syncthreads();

    // transposed, coalesced write: thread -> feature t>>1, node-half t&1
    {
        const int fo = t >> 1, h = t & 1;
        s16x8 v8;
        #pragma unroll
        for (int i = 0; i < 8; ++i) {
            int n = h * 8 + i;
            v8[i] = (nb + n < N_NODES) ? (short)ts[n][fo] : (short)0;
        }
        *reinterpret_cast<s16x8*>(xwt + (size_t)fo * KP + nb + h * 8) = v8;
    }
}

// ---------------------------------------------------------------------------
// Kernel 2: out[i] = relu(A @ XW + b1) @ W2 + b2, fused.
// grid 313 x 256; block = 32 rows x 128 cols; 4 waves split K (interleaved).
// A read f32 (nontemporal, converted to bf16 in-reg), B read from L2-resident xwt.
// ---------------------------------------------------------------------------
__global__ __launch_bounds__(256, 2) void k_gcn(const float* __restrict__ A,
                                                const unsigned short* __restrict__ xwt,
                                                const float* __restrict__ b1,
                                                const float* __restrict__ W2,
                                                const float* __restrict__ b2,
                                                float* __restrict__ out) {
    __shared__ float red[4][32][128];   // 64 KB cross-wave reduction buffer

    const int t     = threadIdx.x;
    const int wave  = t >> 6;
    const int lane  = t & 63;
    const int l16   = lane & 15;
    const int g     = lane >> 4;        // 0..3
    const int rbase = blockIdx.x * 32;

    f32x4 acc[2][8];
    #pragma unroll
    for (int r = 0; r < 2; ++r)
        #pragma unroll
        for (int c = 0; c < 8; ++c) acc[r][c] = (f32x4){0.f, 0.f, 0.f, 0.f};

    int row0 = rbase + l16;      if (row0 > N_NODES - 1) row0 = N_NODES - 1;
    int row1 = rbase + 16 + l16; if (row1 > N_NODES - 1) row1 = N_NODES - 1;
    const float* ap0 = A + (size_t)row0 * N_NODES + 8 * g;
    const float* ap1 = A + (size_t)row1 * N_NODES + 8 * g;
    const unsigned short* bp0 = xwt + (size_t)l16 * KP + 8 * g;

    // main K loop: steps of 32, interleaved across the 4 waves (312 full steps)
    for (int s = wave; s < 312; s += 4) {
        const int k0 = s * 32;
        f32x4 a00 = __builtin_nontemporal_load(reinterpret_cast<const f32x4*>(ap0 + k0));
        f32x4 a01 = __builtin_nontemporal_load(reinterpret_cast<const f32x4*>(ap0 + k0) + 1);
        f32x4 a10 = __builtin_nontemporal_load(reinterpret_cast<const f32x4*>(ap1 + k0));
        f32x4 a11 = __builtin_nontemporal_load(reinterpret_cast<const f32x4*>(ap1 + k0) + 1);
        bf16x8 af0 = pack8(a00, a01);
        bf16x8 af1 = pack8(a10, a11);
        const unsigned short* bp = bp0 + k0;
        #pragma unroll
        for (int c = 0; c < 8; ++c) {
            bf16x8 bf = *reinterpret_cast<const bf16x8*>(bp + (size_t)c * 16 * KP);
            acc[0][c] = __builtin_amdgcn_mfma_f32_16x16x32_bf16(af0, bf, acc[0][c], 0, 0, 0);
            acc[1][c] = __builtin_amdgcn_mfma_f32_16x16x32_bf16(af1, bf, acc[1][c], 0, 0, 0);
        }
    }

    // tail step s=312 (k0=9984, only k<10000 valid): wave 0 only.
    // A lanes with g>=2 would read k>=10000 -> zero them; xwt pad rows are zero.
    if (wave == 0) {
        const int k0 = 9984;
        f32x4 z = (f32x4){0.f, 0.f, 0.f, 0.f};
        f32x4 a00 = z, a01 = z, a10 = z, a11 = z;
        if (g < 2) {
            a00 = *reinterpret_cast<const f32x4*>(ap0 + k0);
            a01 = *(reinterpret_cast<const f32x4*>(ap0 + k0) + 1);
            a10 = *reinterpret_cast<const f32x4*>(ap1 + k0);
            a11 = *(reinterpret_cast<const f32x4*>(ap1 + k0) + 1);
        }
        bf16x8 af0 = pack8(a00, a01);
        bf16x8 af1 = pack8(a10, a11);
        const unsigned short* bp = bp0 + k0;
        #pragma unroll
        for (int c = 0; c < 8; ++c) {
            bf16x8 bf = *reinterpret_cast<const bf16x8*>(bp + (size_t)c * 16 * KP);
            acc[0][c] = __builtin_amdgcn_mfma_f32_16x16x32_bf16(af0, bf, acc[0][c], 0, 0, 0);
            acc[1][c] = __builtin_amdgcn_mfma_f32_16x16x32_bf16(af1, bf, acc[1][c], 0, 0, 0);
        }
    }

    // epilogue: cross-wave reduce + bias + relu + dot(W2) + b2
    // C/D layout (m89): col = lane&15, row = (lane>>4)*4 + reg
    #pragma unroll
    for (int r = 0; r < 2; ++r)
        #pragma unroll
        for (int c = 0; c < 8; ++c)
            #pragma unroll
            for (int e = 0; e < 4; ++e)
                red[wave][r * 16 + g * 4 + e][c * 16 + l16] = acc[r][c][e];
    __syncthreads();

    {
        const int r  = t >> 3;          // 0..31 local row
        const int cb = (t & 7) * 16;    // 8 threads per row, 16 cols each
        float p = 0.f;
        #pragma unroll
        for (int i = 0; i < 16; ++i) {
            int c = cb + i;
            float v = red[0][r][c] + red[1][r][c] + red[2][r][c] + red[3][r][c] + b1[c];
            v = fmaxf(v, 0.f);
            p = fmaf(v, W2[c], p);
        }
        p += __shfl_xor(p, 1);
        p += __shfl_xor(p, 2);
        p += __shfl_xor(p, 4);
        const int grow = rbase + r;
        if ((t & 7) == 0 && grow < N_NODES) out[grow] = p + b2[0];
    }
}

extern "C" void kernel_launch(void* const* d_in, const int* in_sizes, int n_in,
                              void* d_out, int out_size, void* d_ws, size_t ws_size,
                              hipStream_t stream) {
    const float* x  = (const float*)d_in[0];
    const float* a  = (const float*)d_in[1];
    const float* W1 = (const float*)d_in[2];
    const float* b1 = (const float*)d_in[3];
    const float* W2 = (const float*)d_in[4];
    const float* b2 = (const float*)d_in[5];
    float* out = (float*)d_out;
    unsigned short* xwt = (unsigned short*)d_ws;   // 128*10016*2 = 2.56 MB scratch

    k_xw<<<626, 256, 0, stream>>>(x, W1, xwt);
    k_gcn<<<313, 256, 0, stream>>>(a, xwt, b1, W2, b2, out);
}